// Round 4
// baseline (99.767 us; speedup 1.0000x reference)
//
#include <hip/hip_runtime.h>
#include <math.h>

#define NROWS 2048
#define BITS  64
#define NCLS  100
#define ALPHA_C  1.0f
#define LAMBDA_C 1.0f
#define ECLAMP   1.8e19f   // ~sqrt(FLT_MAX): product of two clamped exps can't overflow

// ---------------------------------------------------------------------------
// Fast-path ws layout:
//   [0,      2048) uchar lab8[2048]
//   [8192,  16384) float rl[2048]
//   [16384, 24576) float vl[2048]
//   [24576, 25600) float qp[256]
//   [32768, +16MB) float G[2048][2048]
// Harness poisons the full 256 MiB ws every timed call (~43 us HBM fill) —
// fixed overhead inside the timed window; our kernel budget sits on top.
// ---------------------------------------------------------------------------

__device__ __forceinline__ float block_reduce_sum(float v, float* wsum) {
    __syncthreads();
    #pragma unroll
    for (int off = 32; off > 0; off >>= 1) v += __shfl_down(v, off);
    int tid = threadIdx.x;
    if ((tid & 63) == 0) wsum[tid >> 6] = v;
    __syncthreads();
    float r = 0.f;
    if (tid == 0) {
        #pragma unroll
        for (int w = 0; w < 4; ++w) r += wsum[w];
    }
    return r;
}

__device__ __forceinline__ float softplus_mt(float T) {
    return fmaxf(-T, 0.f) + __logf(1.f + __expf(-fabsf(T)));
}

// ===========================================================================
// Fast path
// ===========================================================================

#define TJ  256
#define SJT 257   // padded LDS row stride (dwords): transpose writes 2-way only

// blocks [0,512): gram, block=(ig 8 i-rows, jh 1024 j-cols). jh==0 also quant.
// blocks [512,1024): labels (4 y-rows/block, one wave each, ballot).
__global__ __launch_bounds__(256) void combo_kernel(const float* __restrict__ u,
                                                    const float* __restrict__ y,
                                                    float* __restrict__ G,
                                                    unsigned char* __restrict__ lab8,
                                                    float* __restrict__ quantp) {
    __shared__ float ujT[64 * SJT];   // 65.8 KB transposed j-tile
    __shared__ float uiT[64 * 8];     // [k][r] i-rows transposed
    __shared__ float wsum[4];
    const int tid = threadIdx.x;

    if (blockIdx.x < 512) {
        const int ig = blockIdx.x >> 1;
        const int jh = blockIdx.x & 1;
        const int i0 = ig * 8;
        const int jb = jh * 1024;

        float qs = 0.f;
        if (jh == 0) {
            #pragma unroll
            for (int t = tid; t < 8 * BITS; t += 256) {
                float v = u[(size_t)i0 * BITS + t];
                float sg = (v > 0.f) ? 1.f : ((v < 0.f) ? -1.f : 0.f);
                float d = v - sg;
                qs = fmaf(d, d, qs);
            }
        }

        // stage i-rows transposed: uiT[k*8+r] = u[(i0+r)*64+k]
        #pragma unroll
        for (int it = 0; it < 2; ++it) {
            const int flat = tid + it * 256;       // 0..511
            const int r = flat >> 6, k = flat & 63;
            uiT[k * 8 + r] = u[(size_t)i0 * BITS + flat];
        }
        if (jh == 0) {
            float qt = block_reduce_sum(qs, wsum);
            if (tid == 0) quantp[ig] = qt;
        }
        __syncthreads();

        for (int jt = 0; jt < 1024 / TJ; ++jt) {
            const int j0 = jb + jt * TJ;
            #pragma unroll
            for (int it = 0; it < 16; ++it) {
                const int flat = tid + it * 256;
                const int r = flat >> 4, q = flat & 15;
                float4 v = *(const float4*)(u + (size_t)(j0 + r) * BITS + q * 4);
                ujT[(4 * q + 0) * SJT + r] = v.x;
                ujT[(4 * q + 1) * SJT + r] = v.y;
                ujT[(4 * q + 2) * SJT + r] = v.z;
                ujT[(4 * q + 3) * SJT + r] = v.w;
            }
            __syncthreads();

            float acc[8];
            #pragma unroll
            for (int r = 0; r < 8; ++r) acc[r] = 0.f;
            #pragma unroll 4
            for (int k = 0; k < BITS; ++k) {
                const float e = ujT[k * SJT + tid];
                const float4 w0 = *(const float4*)&uiT[k * 8 + 0];
                const float4 w1 = *(const float4*)&uiT[k * 8 + 4];
                acc[0] = fmaf(w0.x, e, acc[0]);
                acc[1] = fmaf(w0.y, e, acc[1]);
                acc[2] = fmaf(w0.z, e, acc[2]);
                acc[3] = fmaf(w0.w, e, acc[3]);
                acc[4] = fmaf(w1.x, e, acc[4]);
                acc[5] = fmaf(w1.y, e, acc[5]);
                acc[6] = fmaf(w1.z, e, acc[6]);
                acc[7] = fmaf(w1.w, e, acc[7]);
            }
            #pragma unroll
            for (int r = 0; r < 8; ++r)
                G[(size_t)(i0 + r) * NROWS + j0 + tid] = acc[r];
            __syncthreads();
        }
    } else {
        const int bi = blockIdx.x - 512;
        const int row = bi * 4 + (tid >> 6);
        const int lane = tid & 63;
        const float* yr = y + (size_t)row * NCLS;
        float v0 = yr[lane];
        float v1 = (lane < NCLS - 64) ? yr[lane + 64] : 0.f;
        unsigned long long m0 = __ballot(v0 > 0.5f);
        unsigned long long m1 = __ballot(v1 > 0.5f);
        if (lane == 0) {
            int c = m0 ? (__ffsll(m0) - 1) : (m1 ? 64 + __ffsll(m1) - 1 : 0);
            lab8[row] = (unsigned char)c;
        }
    }
}

// one block per TWO rows (i0=2b, i1=2b+1). Inner eval:
// softplus(-T) = ln2 * log2(1 + E_b * e_p), E_b = exp(a_n+alpha), e_p = exp(-a_p),
// both clamped at sqrt(FLT_MAX). Pos slots: E_b=0 -> exact 0. Both rows'
// pos lists padded to a COMMON x4 bound with e_p=0 (exact 0 contribution),
// interleaved in one loop -> 8 independent log2 chains for trans-pipe ILP.
__global__ __launch_bounds__(256, 4) void eval2_kernel(const float* __restrict__ G,
                                                       const unsigned char* __restrict__ lab8,
                                                       float* __restrict__ rl,
                                                       float* __restrict__ vl) {
    alignas(16) __shared__ float ap0[NROWS + 8];
    alignas(16) __shared__ float ap1[NROWS + 8];
    __shared__ int np0_s, np1_s;
    __shared__ float w0s[4], w1s[4];
    const int i0 = blockIdx.x * 2, i1 = i0 + 1;
    const int tid = threadIdx.x;
    if (tid == 0) { np0_s = 0; np1_s = 0; }
    __syncthreads();
    const int c0 = lab8[i0];
    const int c1 = lab8[i1];

    float av0[8], av1[8];
    int lv[8];
    {
        const float4* g04 = (const float4*)(G + (size_t)i0 * NROWS) + tid * 2;
        const float4* g14 = (const float4*)(G + (size_t)i1 * NROWS) + tid * 2;
        float4 a0 = g04[0], a1 = g04[1];
        float4 b0 = g14[0], b1 = g14[1];
        av0[0] = a0.x; av0[1] = a0.y; av0[2] = a0.z; av0[3] = a0.w;
        av0[4] = a1.x; av0[5] = a1.y; av0[6] = a1.z; av0[7] = a1.w;
        av1[0] = b0.x; av1[1] = b0.y; av1[2] = b0.z; av1[3] = b0.w;
        av1[4] = b1.x; av1[5] = b1.y; av1[6] = b1.z; av1[7] = b1.w;
        uint2 lw = *(const uint2*)(lab8 + (size_t)tid * 8);
        #pragma unroll
        for (int m = 0; m < 4; ++m) lv[m] = (lw.x >> (8 * m)) & 0xFF;
        #pragma unroll
        for (int m = 0; m < 4; ++m) lv[4 + m] = (lw.y >> (8 * m)) & 0xFF;
    }

    float Eb0[8], Eb1[8];
    #pragma unroll
    for (int m = 0; m < 8; ++m) {
        const bool p0 = (lv[m] == c0);
        const bool p1 = (lv[m] == c1);
        if (p0) { int k = atomicAdd(&np0_s, 1); ap0[k] = fminf(__expf(-av0[m]), ECLAMP); }
        if (p1) { int k = atomicAdd(&np1_s, 1); ap1[k] = fminf(__expf(-av1[m]), ECLAMP); }
        Eb0[m] = p0 ? 0.f : fminf(__expf(av0[m] + ALPHA_C), ECLAMP);
        Eb1[m] = p1 ? 0.f : fminf(__expf(av1[m] + ALPHA_C), ECLAMP);
    }
    __syncthreads();
    const int np0 = np0_s, np1 = np1_s;
    const int npr = (((np0 > np1) ? np0 : np1) + 3) & ~3;   // common bound
    for (int k = np0 + tid; k < npr; k += 256) ap0[k] = 0.f;  // pad -> exact 0
    for (int k = np1 + tid; k < npr; k += 256) ap1[k] = 0.f;
    __syncthreads();

    float s0 = 0.f, s1 = 0.f, s2 = 0.f, s3 = 0.f;
    float t0 = 0.f, t1 = 0.f, t2 = 0.f, t3 = 0.f;
    for (int k = 0; k < npr; k += 4) {
        const float4 e0 = *(const float4*)(ap0 + k);   // broadcast reads
        const float4 e1 = *(const float4*)(ap1 + k);
        #pragma unroll
        for (int m = 0; m < 8; ++m) {
            const float q0 = Eb0[m], q1 = Eb1[m];
            s0 += __log2f(fmaf(q0, e0.x, 1.f));
            s1 += __log2f(fmaf(q0, e0.y, 1.f));
            s2 += __log2f(fmaf(q0, e0.z, 1.f));
            s3 += __log2f(fmaf(q0, e0.w, 1.f));
            t0 += __log2f(fmaf(q1, e1.x, 1.f));
            t1 += __log2f(fmaf(q1, e1.y, 1.f));
            t2 += __log2f(fmaf(q1, e1.z, 1.f));
            t3 += __log2f(fmaf(q1, e1.w, 1.f));
        }
    }

    // fused dual-row block reduce (one barrier)
    float r0 = (s0 + s1) + (s2 + s3);
    float r1 = (t0 + t1) + (t2 + t3);
    #pragma unroll
    for (int off = 32; off > 0; off >>= 1) {
        r0 += __shfl_down(r0, off);
        r1 += __shfl_down(r1, off);
    }
    if ((tid & 63) == 0) { w0s[tid >> 6] = r0; w1s[tid >> 6] = r1; }
    __syncthreads();
    if (tid == 0) {
        const float ln2 = 0.6931471805599453f;
        float tot0 = (w0s[0] + w0s[1]) + (w0s[2] + w0s[3]);
        float tot1 = (w1s[0] + w1s[1]) + (w1s[2] + w1s[3]);
        const int nneg0 = NROWS - np0, nneg1 = NROWS - np1;
        const int v0 = (np0 > 0 && nneg0 > 0) ? 1 : 0;
        const int v1 = (np1 > 0 && nneg1 > 0) ? 1 : 0;
        rl[i0] = v0 ? (tot0 * ln2 / fmaxf((float)np0 * (float)nneg0, 1.f)) : 0.f;
        rl[i1] = v1 ? (tot1 * ln2 / fmaxf((float)np1 * (float)nneg1, 1.f)) : 0.f;
        vl[i0] = (float)v0;
        vl[i1] = (float)v1;
    }
}

__global__ __launch_bounds__(256) void finalize2_kernel(const float* __restrict__ rl,
                                                        const float* __restrict__ vl,
                                                        const float* __restrict__ qp,
                                                        float* __restrict__ out) {
    __shared__ float wsum[4];
    const int tid = threadIdx.x;
    float t = 0.f, v = 0.f;
    for (int idx = tid; idx < NROWS; idx += 256) { t += rl[idx]; v += vl[idx]; }
    float q = qp[tid];
    float tt = block_reduce_sum(t, wsum);
    float vv = block_reduce_sum(v, wsum);
    float qq = block_reduce_sum(q, wsum);
    if (tid == 0) {
        const float loss1 = (vv > 0.f) ? (tt / fmaxf(vv, 1.f)) : 0.f;
        const float loss2 = LAMBDA_C * (qq / (float)(NROWS * BITS));
        out[0] = loss1 + loss2;
    }
}

// ===========================================================================
// Fallback path (small ws) — unchanged (passed round 1)
// ===========================================================================

__global__ __launch_bounds__(256) void labels_only_kernel(const float* __restrict__ y,
                                                          int* __restrict__ labels) {
    const int tid = threadIdx.x;
    const int row = blockIdx.x * 4 + (tid >> 6);
    const int lane = tid & 63;
    const float* yr = y + (size_t)row * NCLS;
    float v0 = yr[lane];
    float v1 = (lane < NCLS - 64) ? yr[lane + 64] : 0.f;
    unsigned long long m0 = __ballot(v0 > 0.5f);
    unsigned long long m1 = __ballot(v1 > 0.5f);
    if (lane == 0) {
        int c = m0 ? (__ffsll(m0) - 1) : (m1 ? 64 + __ffsll(m1) - 1 : 0);
        labels[row] = c;
    }
}

__global__ __launch_bounds__(256) void row_loss_kernel(const float* __restrict__ u,
                                                       const int* __restrict__ labels,
                                                       float* __restrict__ acc) {
    __shared__ float a[NROWS];
    __shared__ float apv[NROWS];
    __shared__ int lab[NROWS];
    __shared__ float ui[BITS];
    __shared__ int npos_s;
    __shared__ float wsum[4];

    const int i = blockIdx.x;
    const int tid = threadIdx.x;

    if (tid < BITS) ui[tid] = u[(size_t)i * BITS + tid];
    if (tid == 0) npos_s = 0;
    __syncthreads();

    #pragma unroll
    for (int m = 0; m < NROWS / 256; ++m) {
        const int j = tid + m * 256;
        const float4* uj = (const float4*)(u + (size_t)j * BITS);
        float s0 = 0.f, s1 = 0.f, s2 = 0.f, s3 = 0.f;
        #pragma unroll
        for (int q = 0; q < BITS / 4; ++q) {
            float4 v = uj[q];
            s0 = fmaf(v.x, ui[4 * q + 0], s0);
            s1 = fmaf(v.y, ui[4 * q + 1], s1);
            s2 = fmaf(v.z, ui[4 * q + 2], s2);
            s3 = fmaf(v.w, ui[4 * q + 3], s3);
        }
        a[j] = (s0 + s1) + (s2 + s3);
        lab[j] = labels[j];
    }
    __syncthreads();

    const int c = lab[i];
    #pragma unroll
    for (int m = 0; m < NROWS / 256; ++m) {
        const int j = tid + m * 256;
        if (lab[j] == c) { int k = atomicAdd(&npos_s, 1); apv[k] = a[j]; }
    }
    __syncthreads();
    const int npos = npos_s;
    const int nneg = NROWS - npos;

    float b[NROWS / 256];
    #pragma unroll
    for (int m = 0; m < NROWS / 256; ++m) {
        const int j = tid + m * 256;
        b[m] = (lab[j] != c) ? (a[j] + ALPHA_C) : -3.0e38f;
    }

    float lsum = 0.f;
    for (int k = 0; k < npos; ++k) {
        const float apk = apv[k];
        #pragma unroll
        for (int m = 0; m < NROWS / 256; ++m) lsum += softplus_mt(apk - b[m]);
    }

    float tot = block_reduce_sum(lsum, wsum);
    if (tid == 0) {
        const int valid = (npos > 0 && nneg > 0) ? 1 : 0;
        const float npairs = fmaxf((float)npos * (float)nneg, 1.f);
        const float rlv = valid ? (tot / npairs) : 0.f;
        atomicAdd(&acc[0], rlv);
        atomicAdd(&acc[1], (float)valid);
    }
}

__global__ __launch_bounds__(256) void quant_kernel(const float* __restrict__ u,
                                                    float* __restrict__ acc) {
    __shared__ float wsum[4];
    const int stride = gridDim.x * 256;
    float s = 0.f;
    for (int t = blockIdx.x * 256 + threadIdx.x; t < NROWS * BITS; t += stride) {
        float v = u[t];
        float sg = (v > 0.f) ? 1.f : ((v < 0.f) ? -1.f : 0.f);
        float d = v - sg;
        s = fmaf(d, d, s);
    }
    float tot = block_reduce_sum(s, wsum);
    if (threadIdx.x == 0) atomicAdd(&acc[2], tot);
}

__global__ void finalize_kernel(const float* __restrict__ acc,
                                float* __restrict__ out) {
    const float tot = acc[0], cnt = acc[1], q = acc[2];
    const float loss1 = (cnt > 0.f) ? (tot / fmaxf(cnt, 1.f)) : 0.f;
    const float loss2 = LAMBDA_C * (q / (float)(NROWS * BITS));
    out[0] = loss1 + loss2;
}

// ===========================================================================

extern "C" void kernel_launch(void* const* d_in, const int* in_sizes, int n_in,
                              void* d_out, int out_size, void* d_ws, size_t ws_size,
                              hipStream_t stream) {
    const float* u = (const float*)d_in[0];   // [2048, 64]
    const float* y = (const float*)d_in[1];   // [2048, 100]
    float* out = (float*)d_out;

    unsigned char* lab8 = (unsigned char*)d_ws;
    float* rl = (float*)((char*)d_ws + 8192);
    float* vl = (float*)((char*)d_ws + 16384);
    float* qp = (float*)((char*)d_ws + 24576);
    float* G  = (float*)((char*)d_ws + 32768);
    const size_t NEED = 32768 + (size_t)NROWS * NROWS * sizeof(float);

    if (ws_size >= NEED) {
        combo_kernel<<<1024, 256, 0, stream>>>(u, y, G, lab8, qp);
        eval2_kernel<<<NROWS / 2, 256, 0, stream>>>(G, lab8, rl, vl);
        finalize2_kernel<<<1, 256, 0, stream>>>(rl, vl, qp, out);
    } else {
        float* acc  = (float*)d_ws;
        int*   lab2 = (int*)((char*)d_ws + 256);
        hipMemsetAsync(d_ws, 0, 256, stream);
        labels_only_kernel<<<512, 256, 0, stream>>>(y, lab2);
        row_loss_kernel<<<NROWS, 256, 0, stream>>>(u, lab2, acc);
        quant_kernel<<<64, 256, 0, stream>>>(u, acc);
        finalize_kernel<<<1, 1, 0, stream>>>(acc, out);
    }
}

// Round 5
// 89.971 us; speedup vs baseline: 1.1089x; 1.1089x over previous
//
#include <hip/hip_runtime.h>
#include <hip/hip_bf16.h>
#include <math.h>

#define NROWS 2048
#define BITS  64
#define NCLS  100
#define ALPHA_C  1.0f
#define LAMBDA_C 1.0f
#define ECLAMP   1.8e19f   // ~sqrt(FLT_MAX): product of two clamped exps can't overflow

typedef __bf16 bf16x8 __attribute__((ext_vector_type(8)));
typedef float  floatx4 __attribute__((ext_vector_type(4)));

// ---------------------------------------------------------------------------
// Fast-path ws layout:
//   [0,      2048) uchar lab8[2048]
//   [8192,  16384) float rl[2048]
//   [16384, 24576) float vl[2048]
//   [24576, 24832) float qp[64]
//   [32768, 294912) ushort ub[2048*64]  (bf16 copy of u)
//   [294912, +16MB) float G[2048][2048]
// Harness poisons the full ws every timed call (~43.5 us HBM fill) — fixed
// overhead inside the timed window; our kernel budget sits on top of it.
// ---------------------------------------------------------------------------

__device__ __forceinline__ float block_reduce_sum(float v, float* wsum) {
    __syncthreads();
    #pragma unroll
    for (int off = 32; off > 0; off >>= 1) v += __shfl_down(v, off);
    int tid = threadIdx.x;
    if ((tid & 63) == 0) wsum[tid >> 6] = v;
    __syncthreads();
    float r = 0.f;
    if (tid == 0) {
        #pragma unroll
        for (int w = 0; w < 4; ++w) r += wsum[w];
    }
    return r;
}

__device__ __forceinline__ float softplus_mt(float T) {
    return fmaxf(-T, 0.f) + __logf(1.f + __expf(-fabsf(T)));
}

// ===========================================================================
// Fast path
// ===========================================================================

// blocks [0,64): convert u -> bf16 (RNE) + quant partials (8 elems/thread).
// blocks [64,576): labels via one wave per y-row (ballot).
__global__ __launch_bounds__(256) void prep_kernel(const float* __restrict__ u,
                                                   const float* __restrict__ y,
                                                   unsigned short* __restrict__ ub,
                                                   unsigned char* __restrict__ lab8,
                                                   float* __restrict__ qp) {
    const int tid = threadIdx.x;
    if (blockIdx.x < 64) {
        __shared__ float wsum[4];
        const int base = blockIdx.x * 2048 + tid * 8;
        float4 v0 = *(const float4*)(u + base);
        float4 v1 = *(const float4*)(u + base + 4);
        float vv[8] = {v0.x, v0.y, v0.z, v0.w, v1.x, v1.y, v1.z, v1.w};
        unsigned short ob[8];
        float q = 0.f;
        #pragma unroll
        for (int m = 0; m < 8; ++m) {
            const float v = vv[m];
            const float sg = (v > 0.f) ? 1.f : ((v < 0.f) ? -1.f : 0.f);
            const float d = v - sg;
            q = fmaf(d, d, q);
            __hip_bfloat16 h = __float2bfloat16(v);   // RNE
            ob[m] = *reinterpret_cast<unsigned short*>(&h);
        }
        *(uint4*)(ub + base) = *(const uint4*)ob;
        float t = block_reduce_sum(q, wsum);
        if (tid == 0) qp[blockIdx.x] = t;
    } else {
        const int bi = blockIdx.x - 64;               // 0..511
        const int row = bi * 4 + (tid >> 6);
        const int lane = tid & 63;
        const float* yr = y + (size_t)row * NCLS;
        float v0 = yr[lane];
        float v1 = (lane < NCLS - 64) ? yr[lane + 64] : 0.f;
        unsigned long long m0 = __ballot(v0 > 0.5f);
        unsigned long long m1 = __ballot(v1 > 0.5f);
        if (lane == 0) {
            int c = m0 ? (__ffsll(m0) - 1) : (m1 ? 64 + __ffsll(m1) - 1 : 0);
            lab8[row] = (unsigned char)c;
        }
    }
}

// G = Ub * Ub^T via mfma_f32_16x16x32_bf16.
// Wave w: i-tile ti = w>>5 (16 rows), j-group jg = w&31 (64 cols = 4 subtiles,
// A-fragment reused across subtiles). Layouts (HW-verified per guide):
//   A[m][k]: m = lane&15, k = (lane>>4)*8 + j  (8 contiguous bf16 = 16B load)
//   B[k][n]: n = lane&15, k = (lane>>4)*8 + j  (same pattern, row j0+n)
//   C/D:     col = lane&15, row = (lane>>4)*4 + reg
// (G symmetric -> any consistent transposition is harmless.)
__global__ __launch_bounds__(256) void gram_kernel(const unsigned short* __restrict__ ub,
                                                   float* __restrict__ G) {
    const int tid  = threadIdx.x;
    const int gw   = blockIdx.x * 4 + (tid >> 6);   // 0..4095
    const int lane = tid & 63;
    const int i0   = (gw >> 5) * 16;
    const int j0   = (gw & 31) * 64;
    const int rsel = lane & 15;
    const int quad = lane >> 4;
    const int koff = quad * 8;

    uint4 a0r = *(const uint4*)(ub + (size_t)(i0 + rsel) * BITS + koff);
    uint4 a1r = *(const uint4*)(ub + (size_t)(i0 + rsel) * BITS + 32 + koff);
    bf16x8 A0 = __builtin_bit_cast(bf16x8, a0r);
    bf16x8 A1 = __builtin_bit_cast(bf16x8, a1r);

    #pragma unroll
    for (int s = 0; s < 4; ++s) {
        const int jr = j0 + s * 16 + rsel;
        uint4 b0r = *(const uint4*)(ub + (size_t)jr * BITS + koff);
        uint4 b1r = *(const uint4*)(ub + (size_t)jr * BITS + 32 + koff);
        bf16x8 B0 = __builtin_bit_cast(bf16x8, b0r);
        bf16x8 B1 = __builtin_bit_cast(bf16x8, b1r);
        floatx4 c = {0.f, 0.f, 0.f, 0.f};
        c = __builtin_amdgcn_mfma_f32_16x16x32_bf16(A0, B0, c, 0, 0, 0);
        c = __builtin_amdgcn_mfma_f32_16x16x32_bf16(A1, B1, c, 0, 0, 0);
        #pragma unroll
        for (int r = 0; r < 4; ++r)
            G[(size_t)(i0 + quad * 4 + r) * NROWS + j0 + s * 16 + rsel] = c[r];
    }
}

// one block per TWO rows. softplus(-T) = ln2 * log2(1 + E_b*e_p),
// E_b = exp(a_n+alpha), e_p = exp(-a_p), clamped at sqrt(FLT_MAX).
// Pos slots E_b=0 -> exact 0; pos lists padded to common x4 bound with e_p=0.
__global__ __launch_bounds__(256, 4) void eval2_kernel(const float* __restrict__ G,
                                                       const unsigned char* __restrict__ lab8,
                                                       float* __restrict__ rl,
                                                       float* __restrict__ vl) {
    alignas(16) __shared__ float ap0[NROWS + 8];
    alignas(16) __shared__ float ap1[NROWS + 8];
    __shared__ int np0_s, np1_s;
    __shared__ float w0s[4], w1s[4];
    const int i0 = blockIdx.x * 2, i1 = i0 + 1;
    const int tid = threadIdx.x;
    if (tid == 0) { np0_s = 0; np1_s = 0; }
    __syncthreads();
    const int c0 = lab8[i0];
    const int c1 = lab8[i1];

    float av0[8], av1[8];
    int lv[8];
    {
        const float4* g04 = (const float4*)(G + (size_t)i0 * NROWS) + tid * 2;
        const float4* g14 = (const float4*)(G + (size_t)i1 * NROWS) + tid * 2;
        float4 a0 = g04[0], a1 = g04[1];
        float4 b0 = g14[0], b1 = g14[1];
        av0[0] = a0.x; av0[1] = a0.y; av0[2] = a0.z; av0[3] = a0.w;
        av0[4] = a1.x; av0[5] = a1.y; av0[6] = a1.z; av0[7] = a1.w;
        av1[0] = b0.x; av1[1] = b0.y; av1[2] = b0.z; av1[3] = b0.w;
        av1[4] = b1.x; av1[5] = b1.y; av1[6] = b1.z; av1[7] = b1.w;
        uint2 lw = *(const uint2*)(lab8 + (size_t)tid * 8);
        #pragma unroll
        for (int m = 0; m < 4; ++m) lv[m] = (lw.x >> (8 * m)) & 0xFF;
        #pragma unroll
        for (int m = 0; m < 4; ++m) lv[4 + m] = (lw.y >> (8 * m)) & 0xFF;
    }

    float Eb0[8], Eb1[8];
    #pragma unroll
    for (int m = 0; m < 8; ++m) {
        const bool p0 = (lv[m] == c0);
        const bool p1 = (lv[m] == c1);
        if (p0) { int k = atomicAdd(&np0_s, 1); ap0[k] = fminf(__expf(-av0[m]), ECLAMP); }
        if (p1) { int k = atomicAdd(&np1_s, 1); ap1[k] = fminf(__expf(-av1[m]), ECLAMP); }
        Eb0[m] = p0 ? 0.f : fminf(__expf(av0[m] + ALPHA_C), ECLAMP);
        Eb1[m] = p1 ? 0.f : fminf(__expf(av1[m] + ALPHA_C), ECLAMP);
    }
    __syncthreads();
    const int np0 = np0_s, np1 = np1_s;
    const int npr = (((np0 > np1) ? np0 : np1) + 3) & ~3;
    for (int k = np0 + tid; k < npr; k += 256) ap0[k] = 0.f;
    for (int k = np1 + tid; k < npr; k += 256) ap1[k] = 0.f;
    __syncthreads();

    float s0 = 0.f, s1 = 0.f, s2 = 0.f, s3 = 0.f;
    float t0 = 0.f, t1 = 0.f, t2 = 0.f, t3 = 0.f;
    for (int k = 0; k < npr; k += 4) {
        const float4 e0 = *(const float4*)(ap0 + k);
        const float4 e1 = *(const float4*)(ap1 + k);
        #pragma unroll
        for (int m = 0; m < 8; ++m) {
            const float q0 = Eb0[m], q1 = Eb1[m];
            s0 += __log2f(fmaf(q0, e0.x, 1.f));
            s1 += __log2f(fmaf(q0, e0.y, 1.f));
            s2 += __log2f(fmaf(q0, e0.z, 1.f));
            s3 += __log2f(fmaf(q0, e0.w, 1.f));
            t0 += __log2f(fmaf(q1, e1.x, 1.f));
            t1 += __log2f(fmaf(q1, e1.y, 1.f));
            t2 += __log2f(fmaf(q1, e1.z, 1.f));
            t3 += __log2f(fmaf(q1, e1.w, 1.f));
        }
    }

    float r0 = (s0 + s1) + (s2 + s3);
    float r1 = (t0 + t1) + (t2 + t3);
    #pragma unroll
    for (int off = 32; off > 0; off >>= 1) {
        r0 += __shfl_down(r0, off);
        r1 += __shfl_down(r1, off);
    }
    if ((tid & 63) == 0) { w0s[tid >> 6] = r0; w1s[tid >> 6] = r1; }
    __syncthreads();
    if (tid == 0) {
        const float ln2 = 0.6931471805599453f;
        float tot0 = (w0s[0] + w0s[1]) + (w0s[2] + w0s[3]);
        float tot1 = (w1s[0] + w1s[1]) + (w1s[2] + w1s[3]);
        const int nneg0 = NROWS - np0, nneg1 = NROWS - np1;
        const int v0 = (np0 > 0 && nneg0 > 0) ? 1 : 0;
        const int v1 = (np1 > 0 && nneg1 > 0) ? 1 : 0;
        rl[i0] = v0 ? (tot0 * ln2 / fmaxf((float)np0 * (float)nneg0, 1.f)) : 0.f;
        rl[i1] = v1 ? (tot1 * ln2 / fmaxf((float)np1 * (float)nneg1, 1.f)) : 0.f;
        vl[i0] = (float)v0;
        vl[i1] = (float)v1;
    }
}

__global__ __launch_bounds__(256) void finalize2_kernel(const float* __restrict__ rl,
                                                        const float* __restrict__ vl,
                                                        const float* __restrict__ qp,
                                                        float* __restrict__ out) {
    __shared__ float wsum[4];
    const int tid = threadIdx.x;
    float t = 0.f, v = 0.f;
    for (int idx = tid; idx < NROWS; idx += 256) { t += rl[idx]; v += vl[idx]; }
    float q = (tid < 64) ? qp[tid] : 0.f;
    float tt = block_reduce_sum(t, wsum);
    float vv = block_reduce_sum(v, wsum);
    float qq = block_reduce_sum(q, wsum);
    if (tid == 0) {
        const float loss1 = (vv > 0.f) ? (tt / fmaxf(vv, 1.f)) : 0.f;
        const float loss2 = LAMBDA_C * (qq / (float)(NROWS * BITS));
        out[0] = loss1 + loss2;
    }
}

// ===========================================================================
// Fallback path (small ws) — unchanged (passed round 1)
// ===========================================================================

__global__ __launch_bounds__(256) void labels_only_kernel(const float* __restrict__ y,
                                                          int* __restrict__ labels) {
    const int tid = threadIdx.x;
    const int row = blockIdx.x * 4 + (tid >> 6);
    const int lane = tid & 63;
    const float* yr = y + (size_t)row * NCLS;
    float v0 = yr[lane];
    float v1 = (lane < NCLS - 64) ? yr[lane + 64] : 0.f;
    unsigned long long m0 = __ballot(v0 > 0.5f);
    unsigned long long m1 = __ballot(v1 > 0.5f);
    if (lane == 0) {
        int c = m0 ? (__ffsll(m0) - 1) : (m1 ? 64 + __ffsll(m1) - 1 : 0);
        labels[row] = c;
    }
}

__global__ __launch_bounds__(256) void row_loss_kernel(const float* __restrict__ u,
                                                       const int* __restrict__ labels,
                                                       float* __restrict__ acc) {
    __shared__ float a[NROWS];
    __shared__ float apv[NROWS];
    __shared__ int lab[NROWS];
    __shared__ float ui[BITS];
    __shared__ int npos_s;
    __shared__ float wsum[4];

    const int i = blockIdx.x;
    const int tid = threadIdx.x;

    if (tid < BITS) ui[tid] = u[(size_t)i * BITS + tid];
    if (tid == 0) npos_s = 0;
    __syncthreads();

    #pragma unroll
    for (int m = 0; m < NROWS / 256; ++m) {
        const int j = tid + m * 256;
        const float4* uj = (const float4*)(u + (size_t)j * BITS);
        float s0 = 0.f, s1 = 0.f, s2 = 0.f, s3 = 0.f;
        #pragma unroll
        for (int q = 0; q < BITS / 4; ++q) {
            float4 v = uj[q];
            s0 = fmaf(v.x, ui[4 * q + 0], s0);
            s1 = fmaf(v.y, ui[4 * q + 1], s1);
            s2 = fmaf(v.z, ui[4 * q + 2], s2);
            s3 = fmaf(v.w, ui[4 * q + 3], s3);
        }
        a[j] = (s0 + s1) + (s2 + s3);
        lab[j] = labels[j];
    }
    __syncthreads();

    const int c = lab[i];
    #pragma unroll
    for (int m = 0; m < NROWS / 256; ++m) {
        const int j = tid + m * 256;
        if (lab[j] == c) { int k = atomicAdd(&npos_s, 1); apv[k] = a[j]; }
    }
    __syncthreads();
    const int npos = npos_s;
    const int nneg = NROWS - npos;

    float b[NROWS / 256];
    #pragma unroll
    for (int m = 0; m < NROWS / 256; ++m) {
        const int j = tid + m * 256;
        b[m] = (lab[j] != c) ? (a[j] + ALPHA_C) : -3.0e38f;
    }

    float lsum = 0.f;
    for (int k = 0; k < npos; ++k) {
        const float apk = apv[k];
        #pragma unroll
        for (int m = 0; m < NROWS / 256; ++m) lsum += softplus_mt(apk - b[m]);
    }

    float tot = block_reduce_sum(lsum, wsum);
    if (tid == 0) {
        const int valid = (npos > 0 && nneg > 0) ? 1 : 0;
        const float npairs = fmaxf((float)npos * (float)nneg, 1.f);
        const float rlv = valid ? (tot / npairs) : 0.f;
        atomicAdd(&acc[0], rlv);
        atomicAdd(&acc[1], (float)valid);
    }
}

__global__ __launch_bounds__(256) void quant_kernel(const float* __restrict__ u,
                                                    float* __restrict__ acc) {
    __shared__ float wsum[4];
    const int stride = gridDim.x * 256;
    float s = 0.f;
    for (int t = blockIdx.x * 256 + threadIdx.x; t < NROWS * BITS; t += stride) {
        float v = u[t];
        float sg = (v > 0.f) ? 1.f : ((v < 0.f) ? -1.f : 0.f);
        float d = v - sg;
        s = fmaf(d, d, s);
    }
    float tot = block_reduce_sum(s, wsum);
    if (threadIdx.x == 0) atomicAdd(&acc[2], tot);
}

__global__ void finalize_kernel(const float* __restrict__ acc,
                                float* __restrict__ out) {
    const float tot = acc[0], cnt = acc[1], q = acc[2];
    const float loss1 = (cnt > 0.f) ? (tot / fmaxf(cnt, 1.f)) : 0.f;
    const float loss2 = LAMBDA_C * (q / (float)(NROWS * BITS));
    out[0] = loss1 + loss2;
}

// ===========================================================================

extern "C" void kernel_launch(void* const* d_in, const int* in_sizes, int n_in,
                              void* d_out, int out_size, void* d_ws, size_t ws_size,
                              hipStream_t stream) {
    const float* u = (const float*)d_in[0];   // [2048, 64]
    const float* y = (const float*)d_in[1];   // [2048, 100]
    float* out = (float*)d_out;

    unsigned char* lab8 = (unsigned char*)d_ws;
    float* rl = (float*)((char*)d_ws + 8192);
    float* vl = (float*)((char*)d_ws + 16384);
    float* qp = (float*)((char*)d_ws + 24576);
    unsigned short* ub = (unsigned short*)((char*)d_ws + 32768);
    float* G  = (float*)((char*)d_ws + 294912);
    const size_t NEED = 294912 + (size_t)NROWS * NROWS * sizeof(float);

    if (ws_size >= NEED) {
        prep_kernel<<<576, 256, 0, stream>>>(u, y, ub, lab8, qp);
        gram_kernel<<<1024, 256, 0, stream>>>(ub, G);
        eval2_kernel<<<NROWS / 2, 256, 0, stream>>>(G, lab8, rl, vl);
        finalize2_kernel<<<1, 256, 0, stream>>>(rl, vl, qp, out);
    } else {
        float* acc  = (float*)d_ws;
        int*   lab2 = (int*)((char*)d_ws + 256);
        hipMemsetAsync(d_ws, 0, 256, stream);
        labels_only_kernel<<<512, 256, 0, stream>>>(y, lab2);
        row_loss_kernel<<<NROWS, 256, 0, stream>>>(u, lab2, acc);
        quant_kernel<<<64, 256, 0, stream>>>(u, acc);
        finalize_kernel<<<1, 1, 0, stream>>>(acc, out);
    }
}